// Round 9
// baseline (4561.746 us; speedup 1.0000x reference)
//
#include <hip/hip_runtime.h>
#include <hip/hip_bf16.h>

#define B_ 64
#define S_ 256
#define IN_ 512
#define H_ 1024
#define O_ 512
#define K_ 4
#define T_ (S_*K_)      // 1024
#define H3_ (3*H_)      // 3072

#define NC_ 8           // clusters
#define CPC_ 32         // WGs per cluster
#define RPC_ 8          // batch rows per cluster

typedef __attribute__((ext_vector_type(8))) short bf16x8;
typedef __attribute__((ext_vector_type(4))) float f32x4;
typedef __attribute__((ext_vector_type(4))) unsigned int uint32x4;
typedef unsigned short ushort_t;
typedef unsigned int uint_t;

__device__ __forceinline__ ushort_t f2b(float f) {
    union { float f; unsigned u; } v; v.f = f;
    unsigned r = v.u + 0x7FFFu + ((v.u >> 16) & 1u);
    return (ushort_t)(r >> 16);
}
__device__ __forceinline__ float b2f(ushort_t h) {
    union { unsigned u; float f; } v; v.u = ((unsigned)h) << 16; return v.f;
}

// ---------------------------------------------------------------------------
// gi = x @ W_ih^T + b_ih   (bf16 output), M=16384, N=3072, K=512
// ---------------------------------------------------------------------------
__global__ __launch_bounds__(256) void gi_gemm(const float* __restrict__ x,
                                               const float* __restrict__ Wih,
                                               const float* __restrict__ bih,
                                               ushort_t* __restrict__ gi) {
    const int NB = H3_ / 64;                 // 48
    const int nb = blockIdx.x % NB;
    const int mb = blockIdx.x / NB;
    const int tid = threadIdx.x, lane = tid & 63, w = tid >> 6;
    const int wm = w >> 1, wn = w & 1;
    __shared__ ushort_t Al[64][40];
    __shared__ ushort_t Bl[64][40];
    f32x4 acc[2][2] = {};
    const int lrow = tid >> 2, lk = (tid & 3) * 8;
    for (int k0 = 0; k0 < IN_; k0 += 32) {
        const float* xs = &x[(size_t)(mb*64 + lrow)*IN_ + k0 + lk];
        const float* ws = &Wih[(size_t)(nb*64 + lrow)*IN_ + k0 + lk];
        #pragma unroll
        for (int i = 0; i < 8; ++i) Al[lrow][lk+i] = f2b(xs[i]);
        #pragma unroll
        for (int i = 0; i < 8; ++i) Bl[lrow][lk+i] = f2b(ws[i]);
        __syncthreads();
        const int fr = lane & 15, fk = (lane >> 4) * 8;
        #pragma unroll
        for (int mt = 0; mt < 2; ++mt) {
            bf16x8 a = *(const bf16x8*)&Al[wm*32 + mt*16 + fr][fk];
            #pragma unroll
            for (int nt = 0; nt < 2; ++nt) {
                bf16x8 b = *(const bf16x8*)&Bl[wn*32 + nt*16 + fr][fk];
                acc[mt][nt] = __builtin_amdgcn_mfma_f32_16x16x32_bf16(a, b, acc[mt][nt], 0, 0, 0);
            }
        }
        __syncthreads();
    }
    const int fr = lane & 15, fm = (lane >> 4) * 4;
    #pragma unroll
    for (int mt = 0; mt < 2; ++mt)
    #pragma unroll
    for (int nt = 0; nt < 2; ++nt)
    #pragma unroll
    for (int i = 0; i < 4; ++i) {
        int gm = mb*64 + wm*32 + mt*16 + fm + i;
        int gn = nb*64 + wn*32 + nt*16 + fr;
        gi[(size_t)gm*H3_ + gn] = f2b(acc[mt][nt][i] + bih[gn]);
    }
}

// ---------------------------------------------------------------------------
// Persistent recurrent kernel. 8 clusters x 32 WGs (c=bid&7, cu=bid>>3).
// h-exchange: 32-bit words {tag=t (hi16) | bf16 h (lo16)}, relaxed device-
// scope stores -- tag+data atomic together, so NO flags, NO drains, NO flag
// poll. Readers poll their own A-fragment words until all tags == t-1.
// One __syncthreads per tick (cross-wave red reduce); red double-buffered.
// ---------------------------------------------------------------------------
__global__ __launch_bounds__(256) void rec_kernel(const ushort_t* __restrict__ gi,
                                                  const float* __restrict__ Whh,
                                                  const float* __restrict__ bhh,
                                                  ushort_t* __restrict__ hstates,
                                                  uint_t* __restrict__ xbuf) {
    const int bid = blockIdx.x;
    const int c  = bid & 7;          // cluster
    const int cu = bid >> 3;         // slot within cluster, 0..31
    const int tid = threadIdx.x, lane = tid & 63, w = tid >> 6;
    const int r_el = tid >> 5, jl = tid & 31;   // elementwise mapping (8x32)
    const int fr = lane & 15, koff8 = (lane >> 4) << 3;
    const int colbase = cu << 5;     // 32 h-cols per WG
    const int b0 = c * RPC_;         // batch row base

    __shared__ ushort_t wlds[48][1032];   // 99072 B: rows 0..31 r-gate, 32..47 z-gate lo
    __shared__ float red[2][4][8][100];   // 25600 B  per-wave partials, dbuf

    // ---- stage LDS-resident weight rows (once)
    for (int e = tid * 4; e < 48 * 1024; e += 256 * 4) {
        int rr = e >> 10, k = e & 1023;
        int wrow = (rr < 32) ? (colbase + rr) : (H_ + colbase + (rr - 32));
        const float* src = &Whh[(size_t)wrow*H_ + k];
        #pragma unroll
        for (int i = 0; i < 4; ++i) wlds[rr][k + i] = f2b(src[i]);
    }
    // ---- register-resident weight fragments (once): z hi, n lo, n hi
    bf16x8 bz1[8], bn0[8], bn1[8];
    #pragma unroll
    for (int ks = 0; ks < 8; ++ks) {
        const int kk = (w << 8) + (ks << 5) + koff8;
        const float* sz = &Whh[(size_t)(H_   + colbase + 16 + fr)*H_ + kk];
        const float* s0 = &Whh[(size_t)(2*H_ + colbase      + fr)*H_ + kk];
        const float* s1 = &Whh[(size_t)(2*H_ + colbase + 16 + fr)*H_ + kk];
        bf16x8 tz, t0, t1;
        #pragma unroll
        for (int i = 0; i < 8; ++i) {
            tz[i] = (short)f2b(sz[i]); t0[i] = (short)f2b(s0[i]); t1[i] = (short)f2b(s1[i]);
        }
        bz1[ks] = tz; bn0[ks] = t0; bn1[ks] = t1;
    }
    const float bh_r = bhh[colbase + jl];
    const float bh_z = bhh[H_ + colbase + jl];
    const float bh_n = bhh[2*H_ + colbase + jl];

    // gi double-buffer
    ushort_t g_r, g_z, g_n, p_r = 0, p_z = 0, p_n = 0;
    {
        size_t row = ((size_t)(b0 + r_el)*S_ + 0)*H3_ + colbase + jl;
        g_r = gi[row]; g_z = gi[row + H_]; g_n = gi[row + 2*H_];
    }
    float gir = 0.f, giz = 0.f, gin = 0.f;

    // reader base byte address into xbuf (uint words):
    // cluster region 128KB (c<<17), slot 64KB, row 4KB, col*4B
    const char* xb_lane = (const char*)xbuf
        + ((size_t)c << 17)
        + (size_t)fr * 4096
        + (w << 10)
        + ((lane >> 4) << 5);

    float h_prev = 0.f;
    __syncthreads();                        // wlds ready

    for (int t = 0; t < T_; ++t) {
        // ---- tick top: gi consume (prefetched 4 ticks ago)
        if ((t & 3) == 0) {
            if (t > 0) { g_r = p_r; g_z = p_z; g_n = p_n; }
            gir = b2f(g_r); giz = b2f(g_z); gin = b2f(g_n);
        }

        // ---- A-fragments: tag-validated poll (device scope)
        uint32x4 f0={},f1={},f2={},f3={},f4={},f5={},f6={},f7={};
        uint32x4 f8={},f9={},f10={},f11={},f12={},f13={},f14={},f15={};
        if (t > 0) {
            const char* ab = xb_lane + (((size_t)((t - 1) & 1)) << 16);
            const uint_t tagw = ((uint_t)(t - 1)) << 16;
            for (;;) {
                asm volatile(
                    "global_load_dwordx4 %0, %16, off sc0 sc1\n\t"
                    "global_load_dwordx4 %1, %16, off offset:16 sc0 sc1\n\t"
                    "global_load_dwordx4 %2, %16, off offset:128 sc0 sc1\n\t"
                    "global_load_dwordx4 %3, %16, off offset:144 sc0 sc1\n\t"
                    "global_load_dwordx4 %4, %16, off offset:256 sc0 sc1\n\t"
                    "global_load_dwordx4 %5, %16, off offset:272 sc0 sc1\n\t"
                    "global_load_dwordx4 %6, %16, off offset:384 sc0 sc1\n\t"
                    "global_load_dwordx4 %7, %16, off offset:400 sc0 sc1\n\t"
                    "global_load_dwordx4 %8, %16, off offset:512 sc0 sc1\n\t"
                    "global_load_dwordx4 %9, %16, off offset:528 sc0 sc1\n\t"
                    "global_load_dwordx4 %10, %16, off offset:640 sc0 sc1\n\t"
                    "global_load_dwordx4 %11, %16, off offset:656 sc0 sc1\n\t"
                    "global_load_dwordx4 %12, %16, off offset:768 sc0 sc1\n\t"
                    "global_load_dwordx4 %13, %16, off offset:784 sc0 sc1\n\t"
                    "global_load_dwordx4 %14, %16, off offset:896 sc0 sc1\n\t"
                    "global_load_dwordx4 %15, %16, off offset:912 sc0 sc1\n\t"
                    "s_waitcnt vmcnt(0)"
                    : "=&v"(f0), "=&v"(f1), "=&v"(f2), "=&v"(f3),
                      "=&v"(f4), "=&v"(f5), "=&v"(f6), "=&v"(f7),
                      "=&v"(f8), "=&v"(f9), "=&v"(f10), "=&v"(f11),
                      "=&v"(f12), "=&v"(f13), "=&v"(f14), "=&v"(f15)
                    : "v"(ab)
                    : "memory");
                uint_t acc = 0;
                #define ACC4(F) acc |= (F[0]^tagw); acc |= (F[1]^tagw); \
                                acc |= (F[2]^tagw); acc |= (F[3]^tagw);
                ACC4(f0) ACC4(f1) ACC4(f2) ACC4(f3) ACC4(f4) ACC4(f5) ACC4(f6) ACC4(f7)
                ACC4(f8) ACC4(f9) ACC4(f10) ACC4(f11) ACC4(f12) ACC4(f13) ACC4(f14) ACC4(f15)
                #undef ACC4
                if (__all((fr >= 8) || ((acc & 0xFFFF0000u) == 0u))) break;
            }
            __builtin_amdgcn_sched_barrier(0);
        }
        // unpack lo16 h-data -> bf16x8 fragments
        bf16x8 afr[8];
        {
            union U { uint_t u[4]; bf16x8 v; };
            #define PK(DST, A, B) { U x_; \
                x_.u[0] = (A[0] & 0xffffu) | (A[1] << 16); \
                x_.u[1] = (A[2] & 0xffffu) | (A[3] << 16); \
                x_.u[2] = (B[0] & 0xffffu) | (B[1] << 16); \
                x_.u[3] = (B[2] & 0xffffu) | (B[3] << 16); DST = x_.v; }
            PK(afr[0], f0, f1)   PK(afr[1], f2, f3)
            PK(afr[2], f4, f5)   PK(afr[3], f6, f7)
            PK(afr[4], f8, f9)   PK(afr[5], f10, f11)
            PK(afr[6], f12, f13) PK(afr[7], f14, f15)
            #undef PK
        }

        // ---- MFMA: 6 output tiles (r0,r1,z0,z1,n0,n1) x 8 K-steps
        f32x4 ar0 = {}, ar1 = {}, az0 = {}, az1 = {}, an0 = {}, an1 = {};
        #pragma unroll
        for (int ks = 0; ks < 8; ++ks) {
            const int k = (w << 8) + (ks << 5) + koff8;
            bf16x8 br0 = *(const bf16x8*)&wlds[fr][k];
            bf16x8 br1 = *(const bf16x8*)&wlds[16 + fr][k];
            bf16x8 bz0 = *(const bf16x8*)&wlds[32 + fr][k];
            ar0 = __builtin_amdgcn_mfma_f32_16x16x32_bf16(afr[ks], br0, ar0, 0, 0, 0);
            ar1 = __builtin_amdgcn_mfma_f32_16x16x32_bf16(afr[ks], br1, ar1, 0, 0, 0);
            az0 = __builtin_amdgcn_mfma_f32_16x16x32_bf16(afr[ks], bz0, az0, 0, 0, 0);
            az1 = __builtin_amdgcn_mfma_f32_16x16x32_bf16(afr[ks], bz1[ks], az1, 0, 0, 0);
            an0 = __builtin_amdgcn_mfma_f32_16x16x32_bf16(afr[ks], bn0[ks], an0, 0, 0, 0);
            an1 = __builtin_amdgcn_mfma_f32_16x16x32_bf16(afr[ks], bn1[ks], an1, 0, 0, 0);
        }
        {
            const int par = t & 1;
            if (lane < 32) {                  // C rows 0..7 live in lanes 0..31
                const int m = (lane >> 4) << 2, n = fr;
                #pragma unroll
                for (int i = 0; i < 4; ++i) {
                    red[par][w][m+i][n]      = ar0[i];
                    red[par][w][m+i][16+n]   = ar1[i];
                    red[par][w][m+i][32+n]   = az0[i];
                    red[par][w][m+i][48+n]   = az1[i];
                    red[par][w][m+i][64+n]   = an0[i];
                    red[par][w][m+i][80+n]   = an1[i];
                }
            }
        }
        __syncthreads();   // the ONE barrier per tick

        // ---- elementwise GRU update: thread (r_el, jl), 8x32
        const int par = t & 1;
        float ghr = red[par][0][r_el][jl]    + red[par][1][r_el][jl]    + red[par][2][r_el][jl]    + red[par][3][r_el][jl];
        float ghz = red[par][0][r_el][32+jl] + red[par][1][r_el][32+jl] + red[par][2][r_el][32+jl] + red[par][3][r_el][32+jl];
        float ghn = red[par][0][r_el][64+jl] + red[par][1][r_el][64+jl] + red[par][2][r_el][64+jl] + red[par][3][r_el][64+jl];
        float rr_ = __builtin_amdgcn_rcpf(1.f + __expf(-(gir + ghr + bh_r)));
        float zz  = __builtin_amdgcn_rcpf(1.f + __expf(-(giz + ghz + bh_z)));
        float xx  = gin + rr_ * (ghn + bh_n);
        xx = fminf(fmaxf(xx, -15.f), 15.f);
        float e2  = __expf(2.f * xx);
        float nn  = (e2 - 1.f) * __builtin_amdgcn_rcpf(e2 + 1.f);
        float hn  = (1.f - zz) * nn + zz * h_prev;
        h_prev = hn;
        ushort_t hb = f2b(hn);

        // exchange word {tag | h}: single relaxed device-scope store
        uint_t word = (((uint_t)t) << 16) | (uint_t)hb;
        size_t xidx = ((size_t)c << 15) + ((size_t)(t & 1) << 14) + (r_el << 10) + colbase + jl;
        __hip_atomic_store(&xbuf[xidx], word, __ATOMIC_RELAXED, __HIP_MEMORY_SCOPE_AGENT);

        // trajectory (read by logits_gemm after kernel end): plain store
        hstates[((size_t)(b0 + r_el)*T_ + t)*H_ + colbase + jl] = hb;

        // gi prefetch for s+1 (issued here; drained at next tick's barrier)
        if ((t & 3) == 0) {
            int sn = (t >> 2) + 1; if (sn > S_ - 1) sn = S_ - 1;
            size_t row = ((size_t)(b0 + r_el)*S_ + sn)*H3_ + colbase + jl;
            p_r = gi[row]; p_z = gi[row + H_]; p_n = gi[row + 2*H_];
        }
        // NO trailing barrier: next tick's A-poll enforces cluster progress;
        // red is double-buffered; overwrite-safety via tag happens-before.
    }
}

// ---------------------------------------------------------------------------
// logits = (hstates @ W_fc^T + b_fc) * seq_mask  (f32 out, straight to d_out)
// ---------------------------------------------------------------------------
__global__ __launch_bounds__(256) void logits_gemm(const ushort_t* __restrict__ hstates,
                                                   const float* __restrict__ Wfc,
                                                   const float* __restrict__ bfc,
                                                   const float* __restrict__ sm,
                                                   float* __restrict__ out) {
    const int NB = O_ / 64;                  // 8
    const int nb = blockIdx.x % NB;
    const int mb = blockIdx.x / NB;
    const int tid = threadIdx.x, lane = tid & 63, w = tid >> 6;
    const int wm = w >> 1, wn = w & 1;
    __shared__ ushort_t Al[64][40];
    __shared__ ushort_t Bl[64][40];
    f32x4 acc[2][2] = {};
    const int lrow = tid >> 2, lk = (tid & 3) * 8;
    for (int k0 = 0; k0 < H_; k0 += 32) {
        uint4 va = *(const uint4*)&hstates[(size_t)(mb*64 + lrow)*H_ + k0 + lk];
        *(uint4*)&Al[lrow][lk] = va;
        const float* ws = &Wfc[(size_t)(nb*64 + lrow)*H_ + k0 + lk];
        #pragma unroll
        for (int i = 0; i < 8; ++i) Bl[lrow][lk+i] = f2b(ws[i]);
        __syncthreads();
        const int fr = lane & 15, fk = (lane >> 4) * 8;
        #pragma unroll
        for (int mt = 0; mt < 2; ++mt) {
            bf16x8 a = *(const bf16x8*)&Al[wm*32 + mt*16 + fr][fk];
            #pragma unroll
            for (int nt = 0; nt < 2; ++nt) {
                bf16x8 b = *(const bf16x8*)&Bl[wn*32 + nt*16 + fr][fk];
                acc[mt][nt] = __builtin_amdgcn_mfma_f32_16x16x32_bf16(a, b, acc[mt][nt], 0, 0, 0);
            }
        }
        __syncthreads();
    }
    const int fr = lane & 15, fm = (lane >> 4) * 4;
    #pragma unroll
    for (int mt = 0; mt < 2; ++mt)
    #pragma unroll
    for (int nt = 0; nt < 2; ++nt)
    #pragma unroll
    for (int i = 0; i < 4; ++i) {
        int R  = mb*64 + wm*32 + mt*16 + fm + i;     // b*T + t
        int gn = nb*64 + wn*32 + nt*16 + fr;
        int b  = R >> 10, t = R & (T_ - 1);
        float mval = sm[b*S_ + (t >> 2)];
        out[(size_t)R*O_ + gn] = (acc[mt][nt][i] + bfc[gn]) * mval;
    }
}

// ---------------------------------------------------------------------------
__global__ void tail_kernel(const int* __restrict__ y, const float* __restrict__ sm,
                            float* __restrict__ yout, float* __restrict__ okout) {
    int i = blockIdx.x * 256 + threadIdx.x;
    if (i < B_ * T_) {
        int b = i >> 10, t = i & 1023, s = t >> 2;
        yout[i]  = (float)y[b*S_ + s];
        okout[i] = (sm[b*S_ + s] != 0.0f) ? 1.0f : 0.0f;
    }
}

// ---------------------------------------------------------------------------
extern "C" void kernel_launch(void* const* d_in, const int* in_sizes, int n_in,
                              void* d_out, int out_size, void* d_ws, size_t ws_size,
                              hipStream_t stream) {
    (void)in_sizes; (void)n_in; (void)out_size; (void)ws_size;
    const float* x   = (const float*)d_in[0];
    const int*   y   = (const int*)d_in[1];
    const float* sm  = (const float*)d_in[2];
    const float* Wih = (const float*)d_in[4];
    const float* Whh = (const float*)d_in[5];
    const float* bih = (const float*)d_in[6];
    const float* bhh = (const float*)d_in[7];
    const float* Wfc = (const float*)d_in[8];
    const float* bfc = (const float*)d_in[9];

    char* ws = (char*)d_ws;
    ushort_t* gi      = (ushort_t*)ws;                                  // 100,663,296 B
    ushort_t* hstates = (ushort_t*)(ws + 100663296);                    // 134,217,728 B
    uint_t*   xbuf    = (uint_t*)(ws + 100663296 + 134217728);          //   1,048,576 B

    hipLaunchKernelGGL(gi_gemm, dim3((B_*S_/64)*(H3_/64)), dim3(256), 0, stream,
                       x, Wih, bih, gi);

    void* args[] = { (void*)&gi, (void*)&Whh, (void*)&bhh, (void*)&hstates,
                     (void*)&xbuf };
    hipLaunchCooperativeKernel((void*)rec_kernel, dim3(NC_*CPC_), dim3(256), args, 0, stream);

    hipLaunchKernelGGL(logits_gemm, dim3((B_*T_/64)*(O_/64)), dim3(256), 0, stream,
                       hstates, Wfc, bfc, sm, (float*)d_out);

    float* yout  = (float*)d_out + (size_t)B_*T_*O_;
    float* okout = yout + (size_t)B_*T_;
    hipLaunchKernelGGL(tail_kernel, dim3(B_*T_/256), dim3(256), 0, stream,
                       y, sm, yout, okout);
}

// Round 10
// 3657.720 us; speedup vs baseline: 1.2472x; 1.2472x over previous
//
#include <hip/hip_runtime.h>
#include <hip/hip_bf16.h>

#define B_ 64
#define S_ 256
#define IN_ 512
#define H_ 1024
#define O_ 512
#define K_ 4
#define T_ (S_*K_)      // 1024
#define H3_ (3*H_)      // 3072

#define NC_ 8           // clusters
#define CPC_ 32         // WGs per cluster
#define RPC_ 8          // batch rows per cluster

typedef __attribute__((ext_vector_type(8))) short bf16x8;
typedef __attribute__((ext_vector_type(4))) float f32x4;
typedef __attribute__((ext_vector_type(4))) unsigned int uint32x4;
typedef unsigned short ushort_t;
typedef unsigned int uint_t;

__device__ __forceinline__ ushort_t f2b(float f) {
    union { float f; unsigned u; } v; v.f = f;
    unsigned r = v.u + 0x7FFFu + ((v.u >> 16) & 1u);
    return (ushort_t)(r >> 16);
}
__device__ __forceinline__ float b2f(ushort_t h) {
    union { unsigned u; float f; } v; v.u = ((unsigned)h) << 16; return v.f;
}

// ---------------------------------------------------------------------------
// gi = x @ W_ih^T + b_ih   (bf16 output), M=16384, N=3072, K=512
// ---------------------------------------------------------------------------
__global__ __launch_bounds__(256) void gi_gemm(const float* __restrict__ x,
                                               const float* __restrict__ Wih,
                                               const float* __restrict__ bih,
                                               ushort_t* __restrict__ gi) {
    const int NB = H3_ / 64;                 // 48
    const int nb = blockIdx.x % NB;
    const int mb = blockIdx.x / NB;
    const int tid = threadIdx.x, lane = tid & 63, w = tid >> 6;
    const int wm = w >> 1, wn = w & 1;
    __shared__ ushort_t Al[64][40];
    __shared__ ushort_t Bl[64][40];
    f32x4 acc[2][2] = {};
    const int lrow = tid >> 2, lk = (tid & 3) * 8;
    for (int k0 = 0; k0 < IN_; k0 += 32) {
        const float* xs = &x[(size_t)(mb*64 + lrow)*IN_ + k0 + lk];
        const float* ws = &Wih[(size_t)(nb*64 + lrow)*IN_ + k0 + lk];
        #pragma unroll
        for (int i = 0; i < 8; ++i) Al[lrow][lk+i] = f2b(xs[i]);
        #pragma unroll
        for (int i = 0; i < 8; ++i) Bl[lrow][lk+i] = f2b(ws[i]);
        __syncthreads();
        const int fr = lane & 15, fk = (lane >> 4) * 8;
        #pragma unroll
        for (int mt = 0; mt < 2; ++mt) {
            bf16x8 a = *(const bf16x8*)&Al[wm*32 + mt*16 + fr][fk];
            #pragma unroll
            for (int nt = 0; nt < 2; ++nt) {
                bf16x8 b = *(const bf16x8*)&Bl[wn*32 + nt*16 + fr][fk];
                acc[mt][nt] = __builtin_amdgcn_mfma_f32_16x16x32_bf16(a, b, acc[mt][nt], 0, 0, 0);
            }
        }
        __syncthreads();
    }
    const int fr = lane & 15, fm = (lane >> 4) * 4;
    #pragma unroll
    for (int mt = 0; mt < 2; ++mt)
    #pragma unroll
    for (int nt = 0; nt < 2; ++nt)
    #pragma unroll
    for (int i = 0; i < 4; ++i) {
        int gm = mb*64 + wm*32 + mt*16 + fm + i;
        int gn = nb*64 + wn*32 + nt*16 + fr;
        gi[(size_t)gm*H3_ + gn] = f2b(acc[mt][nt][i] + bih[gn]);
    }
}

// ---------------------------------------------------------------------------
// Persistent recurrent kernel. 256 WGs = 8 clusters x 32 WGs (c=bid&7,
// cu=bid>>3). R8 semantics (agent-scope flags + sc0 sc1 bypass data), with:
//  * dup-row A reads: lane reads row (lane&7) instead of (lane&15) -- the 8
//    pad rows vanish, duplicate addresses coalesce, MALL read traffic halves.
//  * wlds stride 1036 (bank-conflict fix for ds_read_b128 at 16-row stride).
//  * gi prefetch issued right after the A-load so HBM latency drains under
//    compute, not inside the pre-flag barrier drain.
// ---------------------------------------------------------------------------
__global__ __launch_bounds__(256) void rec_kernel(const ushort_t* __restrict__ gi,
                                                  const float* __restrict__ Whh,
                                                  const float* __restrict__ bhh,
                                                  ushort_t* __restrict__ hstates,
                                                  ushort_t* __restrict__ xbuf,
                                                  int* __restrict__ flags) {
    const int bid = blockIdx.x;
    const int c  = bid & 7;          // cluster
    const int cu = bid >> 3;         // slot within cluster, 0..31
    const int tid = threadIdx.x, lane = tid & 63, w = tid >> 6;
    const int r_el = tid >> 5, jl = tid & 31;   // elementwise mapping (8x32)
    const int fr = lane & 15, koff8 = (lane >> 4) << 3;
    const int colbase = cu << 5;     // 32 h-cols per WG
    const int b0 = c * RPC_;         // batch row base

    __shared__ ushort_t wlds[48][1036];   // 99456 B: rows 0..31 r-gate, 32..47 z-gate lo
    __shared__ float red[4][8][100];      // 12800 B  per-wave partials

    // ---- stage LDS-resident weight rows (once)
    for (int e = tid * 4; e < 48 * 1024; e += 256 * 4) {
        int rr = e >> 10, k = e & 1023;
        int wrow = (rr < 32) ? (colbase + rr) : (H_ + colbase + (rr - 32));
        const float* src = &Whh[(size_t)wrow*H_ + k];
        #pragma unroll
        for (int i = 0; i < 4; ++i) wlds[rr][k + i] = f2b(src[i]);
    }
    // ---- register-resident weight fragments (once): z hi, n lo, n hi
    bf16x8 bz1[8], bn0[8], bn1[8];
    #pragma unroll
    for (int ks = 0; ks < 8; ++ks) {
        const int kk = (w << 8) + (ks << 5) + koff8;
        const float* sz = &Whh[(size_t)(H_   + colbase + 16 + fr)*H_ + kk];
        const float* s0 = &Whh[(size_t)(2*H_ + colbase      + fr)*H_ + kk];
        const float* s1 = &Whh[(size_t)(2*H_ + colbase + 16 + fr)*H_ + kk];
        bf16x8 tz, t0, t1;
        #pragma unroll
        for (int i = 0; i < 8; ++i) {
            tz[i] = (short)f2b(sz[i]); t0[i] = (short)f2b(s0[i]); t1[i] = (short)f2b(s1[i]);
        }
        bz1[ks] = tz; bn0[ks] = t0; bn1[ks] = t1;
    }
    const float bh_r = bhh[colbase + jl];
    const float bh_z = bhh[H_ + colbase + jl];
    const float bh_n = bhh[2*H_ + colbase + jl];

    // gi double-buffer
    ushort_t g_r, g_z, g_n, p_r = 0, p_z = 0, p_n = 0;
    {
        size_t row = ((size_t)(b0 + r_el)*S_ + 0)*H3_ + colbase + jl;
        g_r = gi[row]; g_z = gi[row + H_]; g_n = gi[row + 2*H_];
    }
    float gir = 0.f, giz = 0.f, gin = 0.f;

    // per-lane constant part of the A-fragment byte address.
    // DUP-ROW READ: row = lane&7 (not lane&15) -- A rows 8..15 become copies
    // of rows 0..7; their C rows were already discarded. Lanes l and l+8 read
    // identical addresses -> coalesced -> unique MALL read traffic halves.
    const char* xb_lane = (const char*)xbuf
        + ((size_t)c << 16)                 // cluster region (64 KB)
        + (size_t)(lane & 7) * 2048         // row (1024 bf16)
        + (w << 9)                          // wave's K-quarter
        + ((lane >> 4) << 4);               // 16B sub-chunk

    float h_prev = 0.f;
    int* cflags = &flags[c << 5];           // 32 ints per cluster
    __syncthreads();                        // wlds ready

    for (int t = 0; t < T_; ++t) {
        // ---- tick top: gi consume (prefetched 4 ticks ago)
        if ((t & 3) == 0) {
            if (t > 0) { g_r = p_r; g_z = p_z; g_n = p_n; }
            gir = b2f(g_r); giz = b2f(g_z); gin = b2f(g_n);
        }

        // ---- A-fragments: 8 pipelined device-scope loads + one vmcnt(0)
        uint32x4 f0 = {}, f1 = {}, f2 = {}, f3 = {}, f4 = {}, f5 = {}, f6 = {}, f7 = {};
        if (t > 0) {
            const char* ab = xb_lane + (((size_t)((t - 1) & 1)) << 15);
            asm volatile(
                "global_load_dwordx4 %0, %8, off sc0 sc1\n\t"
                "global_load_dwordx4 %1, %8, off offset:64 sc0 sc1\n\t"
                "global_load_dwordx4 %2, %8, off offset:128 sc0 sc1\n\t"
                "global_load_dwordx4 %3, %8, off offset:192 sc0 sc1\n\t"
                "global_load_dwordx4 %4, %8, off offset:256 sc0 sc1\n\t"
                "global_load_dwordx4 %5, %8, off offset:320 sc0 sc1\n\t"
                "global_load_dwordx4 %6, %8, off offset:384 sc0 sc1\n\t"
                "global_load_dwordx4 %7, %8, off offset:448 sc0 sc1\n\t"
                "s_waitcnt vmcnt(0)"
                : "=&v"(f0), "=&v"(f1), "=&v"(f2), "=&v"(f3),
                  "=&v"(f4), "=&v"(f5), "=&v"(f6), "=&v"(f7)
                : "v"(ab)
                : "memory");
            __builtin_amdgcn_sched_barrier(0);
        }
        bf16x8 afr[8];
        afr[0] = *(bf16x8*)&f0; afr[1] = *(bf16x8*)&f1;
        afr[2] = *(bf16x8*)&f2; afr[3] = *(bf16x8*)&f3;
        afr[4] = *(bf16x8*)&f4; afr[5] = *(bf16x8*)&f5;
        afr[6] = *(bf16x8*)&f6; afr[7] = *(bf16x8*)&f7;

        // ---- gi prefetch for s+1: issue NOW so HBM latency hides under the
        // MFMA + barrier instead of extending the pre-flag drain.
        if ((t & 3) == 0) {
            int sn = (t >> 2) + 1; if (sn > S_ - 1) sn = S_ - 1;
            size_t row = ((size_t)(b0 + r_el)*S_ + sn)*H3_ + colbase + jl;
            p_r = gi[row]; p_z = gi[row + H_]; p_n = gi[row + 2*H_];
        }

        // ---- MFMA: 6 output tiles (r0,r1,z0,z1,n0,n1) x 8 K-steps
        f32x4 ar0 = {}, ar1 = {}, az0 = {}, az1 = {}, an0 = {}, an1 = {};
        #pragma unroll
        for (int ks = 0; ks < 8; ++ks) {
            const int k = (w << 8) + (ks << 5) + koff8;
            bf16x8 br0 = *(const bf16x8*)&wlds[fr][k];
            bf16x8 br1 = *(const bf16x8*)&wlds[16 + fr][k];
            bf16x8 bz0 = *(const bf16x8*)&wlds[32 + fr][k];
            ar0 = __builtin_amdgcn_mfma_f32_16x16x32_bf16(afr[ks], br0, ar0, 0, 0, 0);
            ar1 = __builtin_amdgcn_mfma_f32_16x16x32_bf16(afr[ks], br1, ar1, 0, 0, 0);
            az0 = __builtin_amdgcn_mfma_f32_16x16x32_bf16(afr[ks], bz0, az0, 0, 0, 0);
            az1 = __builtin_amdgcn_mfma_f32_16x16x32_bf16(afr[ks], bz1[ks], az1, 0, 0, 0);
            an0 = __builtin_amdgcn_mfma_f32_16x16x32_bf16(afr[ks], bn0[ks], an0, 0, 0, 0);
            an1 = __builtin_amdgcn_mfma_f32_16x16x32_bf16(afr[ks], bn1[ks], an1, 0, 0, 0);
        }
        if (lane < 32) {                      // C rows 0..7 live in lanes 0..31
            const int m = (lane >> 4) << 2, n = fr;
            #pragma unroll
            for (int i = 0; i < 4; ++i) {
                red[w][m+i][n]      = ar0[i];
                red[w][m+i][16+n]   = ar1[i];
                red[w][m+i][32+n]   = az0[i];
                red[w][m+i][48+n]   = az1[i];
                red[w][m+i][64+n]   = an0[i];
                red[w][m+i][80+n]   = an1[i];
            }
        }
        __syncthreads();

        // ---- elementwise GRU update: thread (r_el, jl), 8x32
        float ghr = red[0][r_el][jl]    + red[1][r_el][jl]    + red[2][r_el][jl]    + red[3][r_el][jl];
        float ghz = red[0][r_el][32+jl] + red[1][r_el][32+jl] + red[2][r_el][32+jl] + red[3][r_el][32+jl];
        float ghn = red[0][r_el][64+jl] + red[1][r_el][64+jl] + red[2][r_el][64+jl] + red[3][r_el][64+jl];
        float rr_ = 1.f / (1.f + __expf(-(gir + ghr + bh_r)));
        float zz  = 1.f / (1.f + __expf(-(giz + ghz + bh_z)));
        float nn  = tanhf(gin + rr_ * (ghn + bh_n));
        float hn  = (1.f - zz) * nn + zz * h_prev;
        h_prev = hn;
        ushort_t hb = f2b(hn);

        // trajectory (read by logits_gemm after kernel end): plain store
        hstates[((size_t)(b0 + r_el)*T_ + t)*H_ + colbase + jl] = hb;
        // exchange: agent-scope store into ping-pong slot t&1
        size_t xidx = ((size_t)c << 15) + ((size_t)(t & 1) << 14) + (r_el << 10) + colbase + jl;
        __hip_atomic_store(&xbuf[xidx], hb, __ATOMIC_RELAXED, __HIP_MEMORY_SCOPE_AGENT);

        // barrier drains vmcnt(0) -> stores acked before flag issues
        __syncthreads();

        if (w == 0) {
            if (lane == 0)
                __hip_atomic_store(&cflags[cu], t + 1, __ATOMIC_RELAXED,
                                   __HIP_MEMORY_SCOPE_AGENT);
            for (;;) {
                int v = t + 1;
                if (lane < 32)
                    v = __hip_atomic_load(&cflags[lane], __ATOMIC_RELAXED,
                                          __HIP_MEMORY_SCOPE_AGENT);
                if (__all(v >= t + 1)) break;
                __builtin_amdgcn_s_sleep(1);
            }
        }
        __syncthreads();
    }
}

// ---------------------------------------------------------------------------
// logits = (hstates @ W_fc^T + b_fc) * seq_mask  (f32 out, straight to d_out)
// ---------------------------------------------------------------------------
__global__ __launch_bounds__(256) void logits_gemm(const ushort_t* __restrict__ hstates,
                                                   const float* __restrict__ Wfc,
                                                   const float* __restrict__ bfc,
                                                   const float* __restrict__ sm,
                                                   float* __restrict__ out) {
    const int NB = O_ / 64;                  // 8
    const int nb = blockIdx.x % NB;
    const int mb = blockIdx.x / NB;
    const int tid = threadIdx.x, lane = tid & 63, w = tid >> 6;
    const int wm = w >> 1, wn = w & 1;
    __shared__ ushort_t Al[64][40];
    __shared__ ushort_t Bl[64][40];
    f32x4 acc[2][2] = {};
    const int lrow = tid >> 2, lk = (tid & 3) * 8;
    for (int k0 = 0; k0 < H_; k0 += 32) {
        uint4 va = *(const uint4*)&hstates[(size_t)(mb*64 + lrow)*H_ + k0 + lk];
        *(uint4*)&Al[lrow][lk] = va;
        const float* ws = &Wfc[(size_t)(nb*64 + lrow)*H_ + k0 + lk];
        #pragma unroll
        for (int i = 0; i < 8; ++i) Bl[lrow][lk+i] = f2b(ws[i]);
        __syncthreads();
        const int fr = lane & 15, fk = (lane >> 4) * 8;
        #pragma unroll
        for (int mt = 0; mt < 2; ++mt) {
            bf16x8 a = *(const bf16x8*)&Al[wm*32 + mt*16 + fr][fk];
            #pragma unroll
            for (int nt = 0; nt < 2; ++nt) {
                bf16x8 b = *(const bf16x8*)&Bl[wn*32 + nt*16 + fr][fk];
                acc[mt][nt] = __builtin_amdgcn_mfma_f32_16x16x32_bf16(a, b, acc[mt][nt], 0, 0, 0);
            }
        }
        __syncthreads();
    }
    const int fr = lane & 15, fm = (lane >> 4) * 4;
    #pragma unroll
    for (int mt = 0; mt < 2; ++mt)
    #pragma unroll
    for (int nt = 0; nt < 2; ++nt)
    #pragma unroll
    for (int i = 0; i < 4; ++i) {
        int R  = mb*64 + wm*32 + mt*16 + fm + i;     // b*T + t
        int gn = nb*64 + wn*32 + nt*16 + fr;
        int b  = R >> 10, t = R & (T_ - 1);
        float mval = sm[b*S_ + (t >> 2)];
        out[(size_t)R*O_ + gn] = (acc[mt][nt][i] + bfc[gn]) * mval;
    }
}

// ---------------------------------------------------------------------------
__global__ void tail_kernel(const int* __restrict__ y, const float* __restrict__ sm,
                            float* __restrict__ yout, float* __restrict__ okout) {
    int i = blockIdx.x * 256 + threadIdx.x;
    if (i < B_ * T_) {
        int b = i >> 10, t = i & 1023, s = t >> 2;
        yout[i]  = (float)y[b*S_ + s];
        okout[i] = (sm[b*S_ + s] != 0.0f) ? 1.0f : 0.0f;
    }
}

// ---------------------------------------------------------------------------
extern "C" void kernel_launch(void* const* d_in, const int* in_sizes, int n_in,
                              void* d_out, int out_size, void* d_ws, size_t ws_size,
                              hipStream_t stream) {
    (void)in_sizes; (void)n_in; (void)out_size; (void)ws_size;
    const float* x   = (const float*)d_in[0];
    const int*   y   = (const int*)d_in[1];
    const float* sm  = (const float*)d_in[2];
    const float* Wih = (const float*)d_in[4];
    const float* Whh = (const float*)d_in[5];
    const float* bih = (const float*)d_in[6];
    const float* bhh = (const float*)d_in[7];
    const float* Wfc = (const float*)d_in[8];
    const float* bfc = (const float*)d_in[9];

    char* ws = (char*)d_ws;
    ushort_t* gi      = (ushort_t*)ws;                                  // 100,663,296 B
    ushort_t* hstates = (ushort_t*)(ws + 100663296);                    // 134,217,728 B
    ushort_t* xbuf    = (ushort_t*)(ws + 100663296 + 134217728);        //     524,288 B
    int*      flags   = (int*)(ws + 100663296 + 134217728 + 524288);    //       4 KB

    hipMemsetAsync(flags, 0, 4096, stream);

    hipLaunchKernelGGL(gi_gemm, dim3((B_*S_/64)*(H3_/64)), dim3(256), 0, stream,
                       x, Wih, bih, gi);

    void* args[] = { (void*)&gi, (void*)&Whh, (void*)&bhh, (void*)&hstates,
                     (void*)&xbuf, (void*)&flags };
    hipLaunchCooperativeKernel((void*)rec_kernel, dim3(NC_*CPC_), dim3(256), args, 0, stream);

    hipLaunchKernelGGL(logits_gemm, dim3((B_*T_/64)*(O_/64)), dim3(256), 0, stream,
                       hstates, Wfc, bfc, sm, (float*)d_out);

    float* yout  = (float*)d_out + (size_t)B_*T_*O_;
    float* okout = yout + (size_t)B_*T_;
    hipLaunchKernelGGL(tail_kernel, dim3(B_*T_/256), dim3(256), 0, stream,
                       y, sm, yout, okout);
}